// Round 5
// baseline (349.073 us; speedup 1.0000x reference)
//
#include <hip/hip_runtime.h>
#include <hip/hip_bf16.h>

// ---------------------------------------------------------------------------
// HybridFusionNetworkWithUncertainty — MI355X (gfx950), round 5
// r4 post-mortem: 2 latency windows per K-step (barrier vmcnt(0) drains).
// Fix: BK=64 core, all VMEM issued at one point per iter (one window), LDS
// [128][64] with chunk swizzle q^(r&7) on both DMA-source and reads.
// ws layout (128 MiB, clobber-free, same as r4):
//   [0,64M)   h ; LN in-place ; then zbuf [0,32M), obuf f32 [32M,48M)
//   [64M,128M) wb0-3 (stage A only) ; then qvout (stage C+)
// ---------------------------------------------------------------------------

typedef __bf16 bf16;
typedef __bf16 bf16x4_t __attribute__((ext_vector_type(4)));
typedef __bf16 bf16x8_t __attribute__((ext_vector_type(8)));
typedef float  f32x4_t  __attribute__((ext_vector_type(4)));

__device__ __forceinline__ bf16x8_t cvt8(f32x4_t a, f32x4_t b) {
  bf16x8_t r;
  r[0] = (bf16)a[0]; r[1] = (bf16)a[1]; r[2] = (bf16)a[2]; r[3] = (bf16)a[3];
  r[4] = (bf16)b[0]; r[5] = (bf16)b[1]; r[6] = (bf16)b[2]; r[7] = (bf16)b[3];
  return r;
}

__device__ __forceinline__ void gl_lds16(const void* g, void* l) {
  __builtin_amdgcn_global_load_lds(
      (const __attribute__((address_space(1))) void*)g,
      (__attribute__((address_space(3))) void*)l, 16, 0, 0);
}

// LDS tile: [128 rows][64 bf16] = 16KB, row = 8 chunks of 16B.
// Logical chunk q of row r lives at physical chunk q ^ (r&7).
__device__ __forceinline__ bf16x8_t frag_read64(const bf16* Ts, int row, int q) {
  const int byte = row * 128 + ((q ^ (row & 7)) << 4);
  return *(const bf16x8_t*)((const char*)Ts + byte);
}

// DMA-stage 128x64 bf16 tile: linear LDS dest (wave-uniform base + lane*16),
// swizzle on the per-lane GLOBAL source chunk (m173 pattern).
__device__ __forceinline__ void stage_dma64(const bf16* __restrict__ src, int ld,
                                            int k0, bf16* lds) {
  const int l = threadIdx.x & 63;
  const int w = threadIdx.x >> 6;
#pragma unroll
  for (int j = 0; j < 4; ++j) {
    const int rb = w * 32 + j * 8;          // 8 rows per gl_lds
    const int r  = rb + (l >> 3);
    const int sc = (l & 7) ^ (r & 7);
    gl_lds16(src + (size_t)r * ld + k0 + sc * 8, (char*)lds + rb * 128);
  }
}

// f32 reg-staged 128x64 tile: 2 thr/row, 32 f32 each (8 f32x4)
struct RegTile { f32x4_t v[8]; };
__device__ __forceinline__ void load_reg(RegTile& t, const float* Rf, int k0) {
#pragma unroll
  for (int i = 0; i < 8; ++i) t.v[i] = *(const f32x4_t*)(Rf + k0 + i * 4);
}
__device__ __forceinline__ void commit_reg(const RegTile& t, bf16* lds,
                                           int srow, int shalf) {
#pragma unroll
  for (int c = 0; c < 4; ++c) {
    const int q = shalf * 4 + c;
    const int byte = srow * 128 + ((q ^ (srow & 7)) << 4);
    *(bf16x8_t*)((char*)lds + byte) = cvt8(t.v[2 * c], t.v[2 * c + 1]);
  }
}

// MFMA: 2 k-subtiles x 4x4 16x16x32 fragments per wave (2x2 wave grid)
__device__ __forceinline__ void mfma_step64(const bf16* As, const bf16* Bs,
                                            f32x4_t acc[4][4]) {
  const int lane = threadIdx.x & 63;
  const int wid  = threadIdx.x >> 6;
  const int wm = wid >> 1, wn = wid & 1;
  const int fr = lane & 15, g = lane >> 4;
#pragma unroll
  for (int kk = 0; kk < 2; ++kk) {
    const int q = kk * 4 + g;
    bf16x8_t ar[4], br[4];
#pragma unroll
    for (int mi = 0; mi < 4; ++mi) ar[mi] = frag_read64(As, wm * 64 + mi * 16 + fr, q);
#pragma unroll
    for (int ni = 0; ni < 4; ++ni) br[ni] = frag_read64(Bs, wn * 64 + ni * 16 + fr, q);
#pragma unroll
    for (int mi = 0; mi < 4; ++mi)
#pragma unroll
      for (int ni = 0; ni < 4; ++ni)
        acc[mi][ni] = __builtin_amdgcn_mfma_f32_16x16x32_bf16(ar[mi], br[ni], acc[mi][ni], 0, 0, 0);
  }
}

// Unified BK=64 core: one VMEM issue point -> ONE latency window per iter.
// REG_IS_A=1: A f32 reg-staged, B bf16 DMA.  =0: A bf16 DMA, B f32 reg-staged.
template<int REG_IS_A>
__device__ __forceinline__ void core64(const float* __restrict__ regsrc, int rld,
                                       const bf16* __restrict__ dmasrc, int dld,
                                       int K, bf16* As, bf16* Bs, f32x4_t acc[4][4]) {
  const int tid  = threadIdx.x;
  const int srow = tid >> 1, shalf = tid & 1;
  const float* Rf = regsrc + (size_t)srow * rld + shalf * 32;
  bf16* RegLds = REG_IS_A ? As : Bs;
  bf16* DmaLds = REG_IS_A ? Bs : As;
  RegTile t;
  load_reg(t, Rf, 0);
  for (int k0 = 0; k0 < K; k0 += 64) {
    stage_dma64(dmasrc, dld, k0, DmaLds);       // vmem queue
    commit_reg(t, RegLds, srow, shalf);         // lgkm
    if (k0 + 64 < K) load_reg(t, Rf, k0 + 64);  // vmem queue, BEFORE barrier
    __syncthreads();                            // single drain window
    mfma_step64(As, Bs, acc);
    __syncthreads();
  }
}

// epilogue: local row = wm*64+mi*16+4*(lane>>4)+j ; local col = wn*64+ni*16+(lane&15)
template<int RELU>
__device__ __forceinline__ void epi_bf16(f32x4_t acc[4][4], bf16* __restrict__ C, int ldc,
                                         const float* __restrict__ bias) {
  const int lane = threadIdx.x & 63;
  const int wid  = threadIdx.x >> 6;
  const int wm = wid >> 1, wn = wid & 1;
  const int fr = lane & 15;
  const int rb = wm * 64 + 4 * (lane >> 4);
  const int cb = wn * 64 + fr;
  float bv[4];
#pragma unroll
  for (int ni = 0; ni < 4; ++ni) bv[ni] = bias[cb + ni * 16];
#pragma unroll
  for (int mi = 0; mi < 4; ++mi)
#pragma unroll
    for (int j = 0; j < 4; ++j)
#pragma unroll
      for (int ni = 0; ni < 4; ++ni) {
        float val = acc[mi][ni][j] + bv[ni];
        if (RELU) val = fmaxf(val, 0.f);
        C[(size_t)(rb + mi * 16 + j) * ldc + cb + ni * 16] = (bf16)val;
      }
}

// ---- prep: convert intra weights f32 -> bf16 ----
__device__ __forceinline__ void cp8(bf16* d, const float* s) {
  f32x4_t x0 = *(const f32x4_t*)s;
  f32x4_t x1 = *(const f32x4_t*)(s + 4);
  *(bf16x8_t*)d = cvt8(x0, x1);
}

__global__ __launch_bounds__(256) void prep_kernel(
    const float* __restrict__ w0, const float* __restrict__ w1s,
    const float* __restrict__ w2, const float* __restrict__ w3,
    bf16* __restrict__ o0, bf16* __restrict__ o1,
    bf16* __restrict__ o2, bf16* __restrict__ o3) {
  const int t = blockIdx.x * 256 + threadIdx.x;
  if (t < 65536)       { size_t i = (size_t)t * 8;            cp8(o0 + i, w0 + i); }
  else if (t < 114688) { size_t i = (size_t)(t - 65536) * 8;  cp8(o1 + i, w1s + i); }
  else if (t < 147456) { size_t i = (size_t)(t - 114688) * 8; cp8(o2 + i, w2 + i); }
  else                 { size_t i = (size_t)(t - 147456) * 8; cp8(o3 + i, w3 + i); }
}

// ---- stage A: batched intra GEMM + relu -> h[(b*4+z)*512+n] (bf16) ----
__global__ __launch_bounds__(256) void intra_kernel(
    const float* __restrict__ f0, const float* __restrict__ f1,
    const float* __restrict__ f2, const float* __restrict__ f3,
    const bf16* __restrict__ wb0, const bf16* __restrict__ wb1,
    const bf16* __restrict__ wb2, const bf16* __restrict__ wb3,
    const float* __restrict__ bb0, const float* __restrict__ bb1,
    const float* __restrict__ bb2, const float* __restrict__ bb3,
    bf16* __restrict__ hbuf) {
  __shared__ bf16 As[128 * 64];
  __shared__ bf16 Bs[128 * 64];
  const int bid = blockIdx.x;                     // 2048 blocks
  const int lid = (bid & 7) * 256 + (bid >> 3);   // XCD-chunked bijection
  const int x = lid & 3;                          // N-block
  const int g = lid >> 2;
  const int z = g & 3;                            // model (fast-cycling -> balanced)
  const int y = g >> 2;                           // M-block (0..127)
  const float* fp; const bf16* wp; const float* bp; int K;
  switch (z) {
    case 0:  fp = f0; wp = wb0; bp = bb0; K = 1024; break;
    case 1:  fp = f1; wp = wb1; bp = bb1; K = 768;  break;
    case 2:  fp = f2; wp = wb2; bp = bb2; K = 512;  break;
    default: fp = f3; wp = wb3; bp = bb3; K = 640;  break;
  }
  f32x4_t acc[4][4];
#pragma unroll
  for (int i = 0; i < 4; ++i)
#pragma unroll
    for (int j = 0; j < 4; ++j) acc[i][j] = (f32x4_t){0.f, 0.f, 0.f, 0.f};
  core64<1>(fp + (size_t)(y * 128) * K, K,
            wp + (size_t)(x * 128) * K, K, K, As, Bs, acc);
  bf16* C = hbuf + (size_t)(y * 128) * 2048 + z * 512 + x * 128;
  epi_bf16<1>(acc, C, 2048, bp + x * 128);
}

// ---- stage C: fused q||v projection (65536 x 512, K=512) ----
__global__ __launch_bounds__(256) void qv_kernel(
    const bf16* __restrict__ H, const float* __restrict__ Wq,
    const float* __restrict__ Wv, const float* __restrict__ bq,
    const float* __restrict__ bv, bf16* __restrict__ qvout) {
  __shared__ bf16 As[128 * 64];
  __shared__ bf16 Bs[128 * 64];
  const int bid = blockIdx.x;                     // 2048 blocks
  const int lid = (bid & 7) * 256 + (bid >> 3);
  const int x = lid & 3, y = lid >> 2;            // y: 0..511
  const float* Wsrc = (x < 2) ? Wq : Wv;
  f32x4_t acc[4][4];
#pragma unroll
  for (int i = 0; i < 4; ++i)
#pragma unroll
    for (int j = 0; j < 4; ++j) acc[i][j] = (f32x4_t){0.f, 0.f, 0.f, 0.f};
  core64<0>(Wsrc + (size_t)((x & 1) * 128) * 512, 512,
            H + (size_t)(y * 128) * 512, 512, 512, As, Bs, acc);
  const float* bias = (x < 2) ? bq + x * 128 : bv + (x - 2) * 128;
  epi_bf16<0>(acc, qvout + (size_t)(y * 128) * 512 + x * 128, 512, bias);
}

// ---- stage E: W1 GEMM (K=1024, ldw=1028) + pred_scores rank-4 fixup ----
__global__ __launch_bounds__(256) void w1_kernel(
    const bf16* __restrict__ zb, const float* __restrict__ W1,
    const float* __restrict__ b1, const float* __restrict__ ps,
    float* __restrict__ obuf) {
  __shared__ bf16 As[128 * 64];
  __shared__ bf16 Bs[128 * 64];
  const int bid = blockIdx.x;                     // 256 blocks
  const int lid = (bid & 7) * 32 + (bid >> 3);
  const int x = lid & 1, y = lid >> 1;            // y: 0..127
  f32x4_t acc[4][4];
#pragma unroll
  for (int i = 0; i < 4; ++i)
#pragma unroll
    for (int j = 0; j < 4; ++j) acc[i][j] = (f32x4_t){0.f, 0.f, 0.f, 0.f};
  core64<0>(W1 + (size_t)(x * 128) * 1028, 1028,
            zb + (size_t)(y * 128) * 1024, 1024, 1024, As, Bs, acc);

  const int lane = threadIdx.x & 63;
  const int wid  = threadIdx.x >> 6;
  const int wm = wid >> 1, wn = wid & 1;
  const int fr = lane & 15;
  const int rb = wm * 64 + 4 * (lane >> 4);
  const int cb = x * 128 + wn * 64 + fr;          // global col
  float bv[4], wt[4][4];
#pragma unroll
  for (int ni = 0; ni < 4; ++ni) {
    bv[ni] = b1[cb + ni * 16];
#pragma unroll
    for (int m = 0; m < 4; ++m) wt[ni][m] = W1[(size_t)(cb + ni * 16) * 1028 + 1024 + m];
  }
#pragma unroll
  for (int mi = 0; mi < 4; ++mi)
#pragma unroll
    for (int j = 0; j < 4; ++j) {
      const int r = y * 128 + rb + mi * 16 + j;   // global row
      f32x4_t psv = *(const f32x4_t*)(ps + (size_t)r * 4);
#pragma unroll
      for (int ni = 0; ni < 4; ++ni) {
        float val = acc[mi][ni][j] + bv[ni]
                  + psv[0] * wt[ni][0] + psv[1] * wt[ni][1]
                  + psv[2] * wt[ni][2] + psv[3] * wt[ni][3];
        obuf[(size_t)r * 256 + cb + ni * 16] = val;
      }
    }
}

// ---- LayerNorm over rows of 512, IN-PLACE (bf16), one wave per row ----
__global__ __launch_bounds__(256)
void ln_kernel(bf16* __restrict__ h, const float* __restrict__ g,
               const float* __restrict__ bta) {
  const int row  = blockIdx.x * 4 + (threadIdx.x >> 6);
  const int lane = threadIdx.x & 63;
  bf16* p = h + (size_t)row * 512 + lane * 8;
  const bf16x8_t x = *(const bf16x8_t*)p;
  float xf[8]; float s = 0.f, s2 = 0.f;
#pragma unroll
  for (int j = 0; j < 8; ++j) { xf[j] = (float)x[j]; s += xf[j]; s2 += xf[j] * xf[j]; }
#pragma unroll
  for (int off = 1; off < 64; off <<= 1) { s += __shfl_xor(s, off); s2 += __shfl_xor(s2, off); }
  const float mu  = s * (1.f / 512.f);
  const float var = s2 * (1.f / 512.f) - mu * mu;
  const float inv = rsqrtf(var + 1e-5f);
  f32x4_t g0 = *(const f32x4_t*)(g + lane * 8);
  f32x4_t g1 = *(const f32x4_t*)(g + lane * 8 + 4);
  f32x4_t b0 = *(const f32x4_t*)(bta + lane * 8);
  f32x4_t b1 = *(const f32x4_t*)(bta + lane * 8 + 4);
  bf16x8_t o;
#pragma unroll
  for (int j = 0; j < 4; ++j) o[j]     = (bf16)((xf[j] - mu) * inv * g0[j] + b0[j]);
#pragma unroll
  for (int j = 0; j < 4; ++j) o[4 + j] = (bf16)((xf[4 + j] - mu) * inv * g1[j] + b1[j]);
  *(bf16x8_t*)p = o;
}

// ---- attention: 4x4 scores (k=q per source bug), softmax(-UW*(vi+vj)), z=s@v ----
__global__ __launch_bounds__(256)
void attn_kernel(const bf16* __restrict__ qv, const float* __restrict__ pvars,
                 bf16* __restrict__ z) {
  const int b    = blockIdx.x * 4 + (threadIdx.x >> 6);
  const int lane = threadIdx.x & 63;
  float qf[4][4], vf[4][4];
#pragma unroll
  for (int i = 0; i < 4; ++i) {
    const bf16* row = qv + ((size_t)b * 4 + i) * 512;
    bf16x4_t qq = *(const bf16x4_t*)(row + lane * 4);
    bf16x4_t vv = *(const bf16x4_t*)(row + 256 + lane * 4);
#pragma unroll
    for (int c = 0; c < 4; ++c) { qf[i][c] = (float)qq[c]; vf[i][c] = (float)vv[c]; }
  }
  float s[4][4];
#pragma unroll
  for (int i = 0; i < 4; ++i)
#pragma unroll
    for (int j = 0; j < 4; ++j)
      s[i][j] = qf[i][0] * qf[j][0] + qf[i][1] * qf[j][1] + qf[i][2] * qf[j][2] + qf[i][3] * qf[j][3];
#pragma unroll
  for (int off = 1; off < 64; off <<= 1)
#pragma unroll
    for (int i = 0; i < 4; ++i)
#pragma unroll
      for (int j = 0; j < 4; ++j) s[i][j] += __shfl_xor(s[i][j], off);

  float var4[4];
#pragma unroll
  for (int m = 0; m < 4; ++m) var4[m] = pvars[(size_t)b * 4 + m];
  float w[4][4];
#pragma unroll
  for (int i = 0; i < 4; ++i) {
    float t[4]; float mx = -1e30f;
#pragma unroll
    for (int j = 0; j < 4; ++j) { t[j] = s[i][j] - 0.1f * (var4[i] + var4[j]); mx = fmaxf(mx, t[j]); }
    float sum = 0.f;
#pragma unroll
    for (int j = 0; j < 4; ++j) { t[j] = expf(t[j] - mx); sum += t[j]; }
    const float is = 1.f / sum;
#pragma unroll
    for (int j = 0; j < 4; ++j) w[i][j] = t[j] * is;
  }
#pragma unroll
  for (int i = 0; i < 4; ++i) {
    bf16x4_t zo;
#pragma unroll
    for (int c = 0; c < 4; ++c) {
      float zf = w[i][0] * vf[0][c] + w[i][1] * vf[1][c] + w[i][2] * vf[2][c] + w[i][3] * vf[3][c];
      zo[c] = (bf16)zf;
    }
    *(bf16x4_t*)(z + ((size_t)b * 4 + i) * 256 + lane * 4) = zo;
  }
}

// ---- final fc (256 -> 1) + sigmoid ----
__global__ __launch_bounds__(256)
void fc_kernel(const float* __restrict__ o, const float* __restrict__ wfc,
               const float* __restrict__ bfc, float* __restrict__ out) {
  const int b    = blockIdx.x * 4 + (threadIdx.x >> 6);
  const int lane = threadIdx.x & 63;
  f32x4_t ov = *(const f32x4_t*)(o + (size_t)b * 256 + lane * 4);
  f32x4_t wv = *(const f32x4_t*)(wfc + lane * 4);
  float p = ov[0] * wv[0] + ov[1] * wv[1] + ov[2] * wv[2] + ov[3] * wv[3];
#pragma unroll
  for (int off = 1; off < 64; off <<= 1) p += __shfl_xor(p, off);
  if (lane == 0) {
    const float lg = p + bfc[0];
    out[b] = 1.f / (1.f + expf(-lg));
  }
}

extern "C" void kernel_launch(void* const* d_in, const int* in_sizes, int n_in,
                              void* d_out, int out_size, void* d_ws, size_t ws_size,
                              hipStream_t stream) {
  (void)in_sizes; (void)n_in; (void)out_size; (void)ws_size;
  const float* feat[4] = {(const float*)d_in[0], (const float*)d_in[3],
                          (const float*)d_in[6], (const float*)d_in[9]};
  const float* Wi[4]   = {(const float*)d_in[1], (const float*)d_in[4],
                          (const float*)d_in[7], (const float*)d_in[10]};
  const float* bi[4]   = {(const float*)d_in[2], (const float*)d_in[5],
                          (const float*)d_in[8], (const float*)d_in[11]};
  const float* ps  = (const float*)d_in[12];
  const float* pv  = (const float*)d_in[13];
  const float* lng = (const float*)d_in[14];
  const float* lnb = (const float*)d_in[15];
  const float* Wq  = (const float*)d_in[16];
  const float* bq  = (const float*)d_in[17];
  const float* Wv  = (const float*)d_in[20];
  const float* bvp = (const float*)d_in[21];
  const float* W1  = (const float*)d_in[22];
  const float* b1  = (const float*)d_in[23];
  const float* Wfc = (const float*)d_in[24];
  const float* bfc = (const float*)d_in[25];

  char* ws = (char*)d_ws;
  const size_t MB = 1024 * 1024;
  bf16*  hbuf  = (bf16*)ws;                        // [0,64M): h; LN in-place
  bf16*  zbuf  = (bf16*)ws;                        // [0,32M): z (after stage C)
  float* obuf  = (float*)(ws + 32 * MB);           // [32M,48M)
  bf16*  wb0   = (bf16*)(ws + 64 * MB);            // stage A only
  bf16*  wb1   = (bf16*)(ws + 65 * MB);
  bf16*  wb2   = (bf16*)(ws + 65 * MB + 786432);
  bf16*  wb3   = (bf16*)(ws + 66 * MB + 262144);
  bf16*  qvout = (bf16*)(ws + 64 * MB);            // stage C (clobbers wb*)

  hipLaunchKernelGGL(prep_kernel, dim3(736), dim3(256), 0, stream,
                     Wi[0], Wi[1], Wi[2], Wi[3], wb0, wb1, wb2, wb3);
  hipLaunchKernelGGL(intra_kernel, dim3(2048), dim3(256), 0, stream,
                     feat[0], feat[1], feat[2], feat[3],
                     wb0, wb1, wb2, wb3, bi[0], bi[1], bi[2], bi[3], hbuf);
  hipLaunchKernelGGL(ln_kernel, dim3(65536 / 4), dim3(256), 0, stream, hbuf, lng, lnb);
  hipLaunchKernelGGL(qv_kernel, dim3(2048), dim3(256), 0, stream,
                     hbuf, Wq, Wv, bq, bvp, qvout);
  hipLaunchKernelGGL(attn_kernel, dim3(16384 / 4), dim3(256), 0, stream, qvout, pv, zbuf);
  hipLaunchKernelGGL(w1_kernel, dim3(256), dim3(256), 0, stream, zbuf, W1, b1, ps, obuf);
  hipLaunchKernelGGL(fc_kernel, dim3(16384 / 4), dim3(256), 0, stream, obuf, Wfc, bfc, (float*)d_out);
}

// Round 6
// 279.378 us; speedup vs baseline: 1.2495x; 1.2495x over previous
//
#include <hip/hip_runtime.h>
#include <hip/hip_bf16.h>

// ---------------------------------------------------------------------------
// HybridFusionNetworkWithUncertainty — MI355X (gfx950), round 6
// r5 post-mortem: __syncthreads drains vmcnt(0) -> issuing loads just before
// the barrier exposes full latency. Fix (T4): double-buffered BK=32 tiles,
// counted s_waitcnt vmcnt(6) + raw s_barrier; next tile's loads stay in
// flight across the barrier. f32 operand reg-staged->bf16 commit (2-way
// swizzled); bf16 operand via global_load_lds with source-side swizzle.
// ws layout (128 MiB, clobber-free, as r4):
//   [0,64M)   h ; LN in-place ; then zbuf [0,32M), obuf f32 [32M,48M)
//   [64M,128M) wb0-3 (stage A only) ; then qvout (stage C+)
// ---------------------------------------------------------------------------

typedef __bf16 bf16;
typedef __bf16 bf16x4_t __attribute__((ext_vector_type(4)));
typedef __bf16 bf16x8_t __attribute__((ext_vector_type(8)));
typedef float  f32x4_t  __attribute__((ext_vector_type(4)));

__device__ __forceinline__ bf16x8_t cvt8(f32x4_t a, f32x4_t b) {
  bf16x8_t r;
  r[0] = (bf16)a[0]; r[1] = (bf16)a[1]; r[2] = (bf16)a[2]; r[3] = (bf16)a[3];
  r[4] = (bf16)b[0]; r[5] = (bf16)b[1]; r[6] = (bf16)b[2]; r[7] = (bf16)b[3];
  return r;
}

__device__ __forceinline__ void gl_lds16(const void* g, void* l) {
  __builtin_amdgcn_global_load_lds(
      (const __attribute__((address_space(1))) void*)g,
      (__attribute__((address_space(3))) void*)l, 16, 0, 0);
}

// LDS tile: [128 rows][32 bf16] = 8KB, row = 4 chunks of 16B.
// Logical chunk c of row r lives at physical chunk c ^ ((r>>1)&3).
__device__ __forceinline__ bf16x8_t frag_read(const bf16* Ts, int row, int c0) {
  const int byte = row * 64 + ((c0 ^ ((row >> 1) & 3)) << 4);
  return *(const bf16x8_t*)((const char*)Ts + byte);
}

// DMA-stage 128x32 bf16 tile: linear LDS dest (wave-uniform base + lane*16),
// swizzle applied on the per-lane GLOBAL source chunk (m173 pattern).
__device__ __forceinline__ void stage_b16(const bf16* __restrict__ src, int ld,
                                          int k0, bf16* lds) {
  const int l = threadIdx.x & 63;
  const int w = threadIdx.x >> 6;
#pragma unroll
  for (int j = 0; j < 2; ++j) {
    const int rb = w * 32 + j * 16;
    const int r  = rb + (l >> 2);
    const int sc = (l & 3) ^ ((r >> 1) & 3);
    gl_lds16(src + (size_t)r * ld + k0 + sc * 8, (char*)lds + rb * 64);
  }
}

// commit 16 f32 (4 f32x4) held in regs as bf16x16 = 2 swizzled chunks
__device__ __forceinline__ void commit2(const f32x4_t v[4], bf16* lds,
                                        int srow, int shalf) {
  const int sw = (srow >> 1) & 3;
  *(bf16x8_t*)((char*)lds + srow * 64 + (((shalf * 2)     ^ sw) << 4)) = cvt8(v[0], v[1]);
  *(bf16x8_t*)((char*)lds + srow * 64 + (((shalf * 2 + 1) ^ sw) << 4)) = cvt8(v[2], v[3]);
}

// MFMA step: 4x4 16x16x32 fragments per wave (2x2 wave grid, 64x64 each)
__device__ __forceinline__ void mfma_step(const bf16* As, const bf16* Bs,
                                          f32x4_t acc[4][4]) {
  const int lane = threadIdx.x & 63;
  const int wid  = threadIdx.x >> 6;
  const int wm = wid >> 1, wn = wid & 1;
  const int fr = lane & 15, c0 = lane >> 4;
  bf16x8_t ar[4], br[4];
#pragma unroll
  for (int mi = 0; mi < 4; ++mi) ar[mi] = frag_read(As, wm * 64 + mi * 16 + fr, c0);
#pragma unroll
  for (int ni = 0; ni < 4; ++ni) br[ni] = frag_read(Bs, wn * 64 + ni * 16 + fr, c0);
#pragma unroll
  for (int mi = 0; mi < 4; ++mi)
#pragma unroll
    for (int ni = 0; ni < 4; ++ni)
      acc[mi][ni] = __builtin_amdgcn_mfma_f32_16x16x32_bf16(ar[mi], br[ni], acc[mi][ni], 0, 0, 0);
}

#define WAIT_VM6()  asm volatile("s_waitcnt vmcnt(6)" ::: "memory")
#define WAIT_VM0()  asm volatile("s_waitcnt vmcnt(0)" ::: "memory")
#define WAIT_LGKM() asm volatile("s_waitcnt lgkmcnt(0)" ::: "memory")
#define SBAR()      __builtin_amdgcn_s_barrier()
#define SCHED0()    __builtin_amdgcn_sched_barrier(0)

// Double-buffered BK=32 core with counted vmcnt (T4).
// REG_IS_A=1: reg operand (f32) is A, DMA operand (bf16) is B; =0: swapped.
// K must be a multiple of 64.
template<int REG_IS_A>
__device__ __forceinline__ void core_db(
    const float* __restrict__ regsrc, int rld,
    const bf16* __restrict__ dmasrc, int dld, int K,
    bf16* R0, bf16* R1, bf16* D0, bf16* D1, f32x4_t acc[4][4])
{
  const int tid  = threadIdx.x;
  const int srow = tid >> 1, shalf = tid & 1;
  const float* Rf = regsrc + (size_t)srow * rld + shalf * 16;

  f32x4_t ra[4], rb[4];
#pragma unroll
  for (int i = 0; i < 4; ++i) ra[i] = *(const f32x4_t*)(Rf + i * 4);
  stage_b16(dmasrc, dld, 0, D0);                 // tile 0 -> buf0 (6 vm ops total)

  for (int k0 = 0; k0 < K; k0 += 64) {
    // ---- half 1: compute tile k0 (buf0); stage tile k0+32 (buf1) ----
    stage_b16(dmasrc, dld, k0 + 32, D1);
#pragma unroll
    for (int i = 0; i < 4; ++i) rb[i] = *(const f32x4_t*)(Rf + k0 + 32 + i * 4);
    WAIT_VM6();                                  // tile k0 (older 6) retired
    commit2(ra, R0, srow, shalf);
    WAIT_LGKM();
    SBAR(); SCHED0();
    if (REG_IS_A) mfma_step(R0, D0, acc); else mfma_step(D0, R0, acc);
    SCHED0(); SBAR();
    // ---- half 2: compute tile k0+32 (buf1); stage tile k0+64 (buf0) ----
    if (k0 + 64 < K) {
      stage_b16(dmasrc, dld, k0 + 64, D0);
#pragma unroll
      for (int i = 0; i < 4; ++i) ra[i] = *(const f32x4_t*)(Rf + k0 + 64 + i * 4);
      WAIT_VM6();
    } else {
      WAIT_VM0();
    }
    commit2(rb, R1, srow, shalf);
    WAIT_LGKM();
    SBAR(); SCHED0();
    if (REG_IS_A) mfma_step(R1, D1, acc); else mfma_step(D1, R1, acc);
    SCHED0(); SBAR();
  }
}

// epilogue: local row = wm*64+mi*16+4*(lane>>4)+j ; local col = wn*64+ni*16+(lane&15)
template<int RELU>
__device__ __forceinline__ void epi_bf16(f32x4_t acc[4][4], bf16* __restrict__ C, int ldc,
                                         const float* __restrict__ bias) {
  const int lane = threadIdx.x & 63;
  const int wid  = threadIdx.x >> 6;
  const int wm = wid >> 1, wn = wid & 1;
  const int fr = lane & 15;
  const int rb = wm * 64 + 4 * (lane >> 4);
  const int cb = wn * 64 + fr;
  float bv[4];
#pragma unroll
  for (int ni = 0; ni < 4; ++ni) bv[ni] = bias[cb + ni * 16];
#pragma unroll
  for (int mi = 0; mi < 4; ++mi)
#pragma unroll
    for (int j = 0; j < 4; ++j)
#pragma unroll
      for (int ni = 0; ni < 4; ++ni) {
        float val = acc[mi][ni][j] + bv[ni];
        if (RELU) val = fmaxf(val, 0.f);
        C[(size_t)(rb + mi * 16 + j) * ldc + cb + ni * 16] = (bf16)val;
      }
}

// ---- prep: convert intra weights f32 -> bf16 ----
__device__ __forceinline__ void cp8(bf16* d, const float* s) {
  f32x4_t x0 = *(const f32x4_t*)s;
  f32x4_t x1 = *(const f32x4_t*)(s + 4);
  *(bf16x8_t*)d = cvt8(x0, x1);
}

__global__ __launch_bounds__(256) void prep_kernel(
    const float* __restrict__ w0, const float* __restrict__ w1s,
    const float* __restrict__ w2, const float* __restrict__ w3,
    bf16* __restrict__ o0, bf16* __restrict__ o1,
    bf16* __restrict__ o2, bf16* __restrict__ o3) {
  const int t = blockIdx.x * 256 + threadIdx.x;
  if (t < 65536)       { size_t i = (size_t)t * 8;            cp8(o0 + i, w0 + i); }
  else if (t < 114688) { size_t i = (size_t)(t - 65536) * 8;  cp8(o1 + i, w1s + i); }
  else if (t < 147456) { size_t i = (size_t)(t - 114688) * 8; cp8(o2 + i, w2 + i); }
  else                 { size_t i = (size_t)(t - 147456) * 8; cp8(o3 + i, w3 + i); }
}

// ---- stage A: batched intra GEMM + relu -> h[(b*4+z)*512+n] (bf16) ----
__global__ __launch_bounds__(256) void intra_kernel(
    const float* __restrict__ f0, const float* __restrict__ f1,
    const float* __restrict__ f2, const float* __restrict__ f3,
    const bf16* __restrict__ wb0, const bf16* __restrict__ wb1,
    const bf16* __restrict__ wb2, const bf16* __restrict__ wb3,
    const float* __restrict__ bb0, const float* __restrict__ bb1,
    const float* __restrict__ bb2, const float* __restrict__ bb3,
    bf16* __restrict__ hbuf) {
  __shared__ bf16 A0[128 * 32], A1[128 * 32], B0[128 * 32], B1[128 * 32];
  const int bid = blockIdx.x;                     // 2048 blocks
  const int lid = (bid & 7) * 256 + (bid >> 3);   // XCD-chunked bijection
  const int x = lid & 3;                          // N-block
  const int g = lid >> 2;
  const int z = g & 3;                            // model (fast-cycling -> balanced)
  const int y = g >> 2;                           // M-block (0..127)
  const float* fp; const bf16* wp; const float* bp; int K;
  switch (z) {
    case 0:  fp = f0; wp = wb0; bp = bb0; K = 1024; break;
    case 1:  fp = f1; wp = wb1; bp = bb1; K = 768;  break;
    case 2:  fp = f2; wp = wb2; bp = bb2; K = 512;  break;
    default: fp = f3; wp = wb3; bp = bb3; K = 640;  break;
  }
  f32x4_t acc[4][4];
#pragma unroll
  for (int i = 0; i < 4; ++i)
#pragma unroll
    for (int j = 0; j < 4; ++j) acc[i][j] = (f32x4_t){0.f, 0.f, 0.f, 0.f};
  core_db<1>(fp + (size_t)(y * 128) * K, K,
             wp + (size_t)(x * 128) * K, K, K, A0, A1, B0, B1, acc);
  bf16* C = hbuf + (size_t)(y * 128) * 2048 + z * 512 + x * 128;
  epi_bf16<1>(acc, C, 2048, bp + x * 128);
}

// ---- stage C: fused q||v projection (65536 x 512, K=512) ----
__global__ __launch_bounds__(256) void qv_kernel(
    const bf16* __restrict__ H, const float* __restrict__ Wq,
    const float* __restrict__ Wv, const float* __restrict__ bq,
    const float* __restrict__ bv, bf16* __restrict__ qvout) {
  __shared__ bf16 A0[128 * 32], A1[128 * 32], B0[128 * 32], B1[128 * 32];
  const int bid = blockIdx.x;                     // 2048 blocks
  const int lid = (bid & 7) * 256 + (bid >> 3);
  const int x = lid & 3, y = lid >> 2;            // y: 0..511
  const float* Wsrc = (x < 2) ? Wq : Wv;
  f32x4_t acc[4][4];
#pragma unroll
  for (int i = 0; i < 4; ++i)
#pragma unroll
    for (int j = 0; j < 4; ++j) acc[i][j] = (f32x4_t){0.f, 0.f, 0.f, 0.f};
  // reg operand = weights (B), DMA operand = H (A)
  core_db<0>(Wsrc + (size_t)((x & 1) * 128) * 512, 512,
             H + (size_t)(y * 128) * 512, 512, 512, B0, B1, A0, A1, acc);
  const float* bias = (x < 2) ? bq + x * 128 : bv + (x - 2) * 128;
  epi_bf16<0>(acc, qvout + (size_t)(y * 128) * 512 + x * 128, 512, bias);
}

// ---- stage E: W1 GEMM (K=1024, ldw=1028) + pred_scores rank-4 fixup ----
__global__ __launch_bounds__(256) void w1_kernel(
    const bf16* __restrict__ zb, const float* __restrict__ W1,
    const float* __restrict__ b1, const float* __restrict__ ps,
    float* __restrict__ obuf) {
  __shared__ bf16 A0[128 * 32], A1[128 * 32], B0[128 * 32], B1[128 * 32];
  const int bid = blockIdx.x;                     // 256 blocks
  const int lid = (bid & 7) * 32 + (bid >> 3);
  const int x = lid & 1, y = lid >> 1;            // y: 0..127
  f32x4_t acc[4][4];
#pragma unroll
  for (int i = 0; i < 4; ++i)
#pragma unroll
    for (int j = 0; j < 4; ++j) acc[i][j] = (f32x4_t){0.f, 0.f, 0.f, 0.f};
  core_db<0>(W1 + (size_t)(x * 128) * 1028, 1028,
             zb + (size_t)(y * 128) * 1024, 1024, 1024, B0, B1, A0, A1, acc);

  const int lane = threadIdx.x & 63;
  const int wid  = threadIdx.x >> 6;
  const int wm = wid >> 1, wn = wid & 1;
  const int fr = lane & 15;
  const int rb = wm * 64 + 4 * (lane >> 4);
  const int cb = x * 128 + wn * 64 + fr;          // global col
  float bv[4], wt[4][4];
#pragma unroll
  for (int ni = 0; ni < 4; ++ni) {
    bv[ni] = b1[cb + ni * 16];
#pragma unroll
    for (int m = 0; m < 4; ++m) wt[ni][m] = W1[(size_t)(cb + ni * 16) * 1028 + 1024 + m];
  }
#pragma unroll
  for (int mi = 0; mi < 4; ++mi)
#pragma unroll
    for (int j = 0; j < 4; ++j) {
      const int r = y * 128 + rb + mi * 16 + j;   // global row
      f32x4_t psv = *(const f32x4_t*)(ps + (size_t)r * 4);
#pragma unroll
      for (int ni = 0; ni < 4; ++ni) {
        float val = acc[mi][ni][j] + bv[ni]
                  + psv[0] * wt[ni][0] + psv[1] * wt[ni][1]
                  + psv[2] * wt[ni][2] + psv[3] * wt[ni][3];
        obuf[(size_t)r * 256 + cb + ni * 16] = val;
      }
    }
}

// ---- LayerNorm over rows of 512, IN-PLACE (bf16), one wave per row ----
__global__ __launch_bounds__(256)
void ln_kernel(bf16* __restrict__ h, const float* __restrict__ g,
               const float* __restrict__ bta) {
  const int row  = blockIdx.x * 4 + (threadIdx.x >> 6);
  const int lane = threadIdx.x & 63;
  bf16* p = h + (size_t)row * 512 + lane * 8;
  const bf16x8_t x = *(const bf16x8_t*)p;
  float xf[8]; float s = 0.f, s2 = 0.f;
#pragma unroll
  for (int j = 0; j < 8; ++j) { xf[j] = (float)x[j]; s += xf[j]; s2 += xf[j] * xf[j]; }
#pragma unroll
  for (int off = 1; off < 64; off <<= 1) { s += __shfl_xor(s, off); s2 += __shfl_xor(s2, off); }
  const float mu  = s * (1.f / 512.f);
  const float var = s2 * (1.f / 512.f) - mu * mu;
  const float inv = rsqrtf(var + 1e-5f);
  f32x4_t g0 = *(const f32x4_t*)(g + lane * 8);
  f32x4_t g1 = *(const f32x4_t*)(g + lane * 8 + 4);
  f32x4_t b0 = *(const f32x4_t*)(bta + lane * 8);
  f32x4_t b1 = *(const f32x4_t*)(bta + lane * 8 + 4);
  bf16x8_t o;
#pragma unroll
  for (int j = 0; j < 4; ++j) o[j]     = (bf16)((xf[j] - mu) * inv * g0[j] + b0[j]);
#pragma unroll
  for (int j = 0; j < 4; ++j) o[4 + j] = (bf16)((xf[4 + j] - mu) * inv * g1[j] + b1[j]);
  *(bf16x8_t*)p = o;
}

// ---- attention: 4x4 scores (k=q per source bug), softmax(-UW*(vi+vj)), z=s@v ----
__global__ __launch_bounds__(256)
void attn_kernel(const bf16* __restrict__ qv, const float* __restrict__ pvars,
                 bf16* __restrict__ z) {
  const int b    = blockIdx.x * 4 + (threadIdx.x >> 6);
  const int lane = threadIdx.x & 63;
  float qf[4][4], vf[4][4];
#pragma unroll
  for (int i = 0; i < 4; ++i) {
    const bf16* row = qv + ((size_t)b * 4 + i) * 512;
    bf16x4_t qq = *(const bf16x4_t*)(row + lane * 4);
    bf16x4_t vv = *(const bf16x4_t*)(row + 256 + lane * 4);
#pragma unroll
    for (int c = 0; c < 4; ++c) { qf[i][c] = (float)qq[c]; vf[i][c] = (float)vv[c]; }
  }
  float s[4][4];
#pragma unroll
  for (int i = 0; i < 4; ++i)
#pragma unroll
    for (int j = 0; j < 4; ++j)
      s[i][j] = qf[i][0] * qf[j][0] + qf[i][1] * qf[j][1] + qf[i][2] * qf[j][2] + qf[i][3] * qf[j][3];
#pragma unroll
  for (int off = 1; off < 64; off <<= 1)
#pragma unroll
    for (int i = 0; i < 4; ++i)
#pragma unroll
      for (int j = 0; j < 4; ++j) s[i][j] += __shfl_xor(s[i][j], off);

  float var4[4];
#pragma unroll
  for (int m = 0; m < 4; ++m) var4[m] = pvars[(size_t)b * 4 + m];
  float w[4][4];
#pragma unroll
  for (int i = 0; i < 4; ++i) {
    float t[4]; float mx = -1e30f;
#pragma unroll
    for (int j = 0; j < 4; ++j) { t[j] = s[i][j] - 0.1f * (var4[i] + var4[j]); mx = fmaxf(mx, t[j]); }
    float sum = 0.f;
#pragma unroll
    for (int j = 0; j < 4; ++j) { t[j] = expf(t[j] - mx); sum += t[j]; }
    const float is = 1.f / sum;
#pragma unroll
    for (int j = 0; j < 4; ++j) w[i][j] = t[j] * is;
  }
#pragma unroll
  for (int i = 0; i < 4; ++i) {
    bf16x4_t zo;
#pragma unroll
    for (int c = 0; c < 4; ++c) {
      float zf = w[i][0] * vf[0][c] + w[i][1] * vf[1][c] + w[i][2] * vf[2][c] + w[i][3] * vf[3][c];
      zo[c] = (bf16)zf;
    }
    *(bf16x4_t*)(z + ((size_t)b * 4 + i) * 256 + lane * 4) = zo;
  }
}

// ---- final fc (256 -> 1) + sigmoid ----
__global__ __launch_bounds__(256)
void fc_kernel(const float* __restrict__ o, const float* __restrict__ wfc,
               const float* __restrict__ bfc, float* __restrict__ out) {
  const int b    = blockIdx.x * 4 + (threadIdx.x >> 6);
  const int lane = threadIdx.x & 63;
  f32x4_t ov = *(const f32x4_t*)(o + (size_t)b * 256 + lane * 4);
  f32x4_t wv = *(const f32x4_t*)(wfc + lane * 4);
  float p = ov[0] * wv[0] + ov[1] * wv[1] + ov[2] * wv[2] + ov[3] * wv[3];
#pragma unroll
  for (int off = 1; off < 64; off <<= 1) p += __shfl_xor(p, off);
  if (lane == 0) {
    const float lg = p + bfc[0];
    out[b] = 1.f / (1.f + expf(-lg));
  }
}

extern "C" void kernel_launch(void* const* d_in, const int* in_sizes, int n_in,
                              void* d_out, int out_size, void* d_ws, size_t ws_size,
                              hipStream_t stream) {
  (void)in_sizes; (void)n_in; (void)out_size; (void)ws_size;
  const float* feat[4] = {(const float*)d_in[0], (const float*)d_in[3],
                          (const float*)d_in[6], (const float*)d_in[9]};
  const float* Wi[4]   = {(const float*)d_in[1], (const float*)d_in[4],
                          (const float*)d_in[7], (const float*)d_in[10]};
  const float* bi[4]   = {(const float*)d_in[2], (const float*)d_in[5],
                          (const float*)d_in[8], (const float*)d_in[11]};
  const float* ps  = (const float*)d_in[12];
  const float* pv  = (const float*)d_in[13];
  const float* lng = (const float*)d_in[14];
  const float* lnb = (const float*)d_in[15];
  const float* Wq  = (const float*)d_in[16];
  const float* bq  = (const float*)d_in[17];
  const float* Wv  = (const float*)d_in[20];
  const float* bvp = (const float*)d_in[21];
  const float* W1  = (const float*)d_in[22];
  const float* b1  = (const float*)d_in[23];
  const float* Wfc = (const float*)d_in[24];
  const float* bfc = (const float*)d_in[25];

  char* ws = (char*)d_ws;
  const size_t MB = 1024 * 1024;
  bf16*  hbuf  = (bf16*)ws;                        // [0,64M): h; LN in-place
  bf16*  zbuf  = (bf16*)ws;                        // [0,32M): z (after stage C)
  float* obuf  = (float*)(ws + 32 * MB);           // [32M,48M)
  bf16*  wb0   = (bf16*)(ws + 64 * MB);            // stage A only
  bf16*  wb1   = (bf16*)(ws + 65 * MB);
  bf16*  wb2   = (bf16*)(ws + 65 * MB + 786432);
  bf16*  wb3   = (bf16*)(ws + 66 * MB + 262144);
  bf16*  qvout = (bf16*)(ws + 64 * MB);            // stage C (clobbers wb*)

  hipLaunchKernelGGL(prep_kernel, dim3(736), dim3(256), 0, stream,
                     Wi[0], Wi[1], Wi[2], Wi[3], wb0, wb1, wb2, wb3);
  hipLaunchKernelGGL(intra_kernel, dim3(2048), dim3(256), 0, stream,
                     feat[0], feat[1], feat[2], feat[3],
                     wb0, wb1, wb2, wb3, bi[0], bi[1], bi[2], bi[3], hbuf);
  hipLaunchKernelGGL(ln_kernel, dim3(65536 / 4), dim3(256), 0, stream, hbuf, lng, lnb);
  hipLaunchKernelGGL(qv_kernel, dim3(2048), dim3(256), 0, stream,
                     hbuf, Wq, Wv, bq, bvp, qvout);
  hipLaunchKernelGGL(attn_kernel, dim3(16384 / 4), dim3(256), 0, stream, qvout, pv, zbuf);
  hipLaunchKernelGGL(w1_kernel, dim3(256), dim3(256), 0, stream, zbuf, W1, b1, ps, obuf);
  hipLaunchKernelGGL(fc_kernel, dim3(16384 / 4), dim3(256), 0, stream, obuf, Wfc, bfc, (float*)d_out);
}

// Round 7
// 255.414 us; speedup vs baseline: 1.3667x; 1.0938x over previous
//
#include <hip/hip_runtime.h>
#include <hip/hip_bf16.h>

// ---------------------------------------------------------------------------
// HybridFusionNetworkWithUncertainty — MI355X (gfx950), round 7
// Fused intra GEMM + ReLU + LayerNorm: BM=64 x BN=512(full hidden) x BK=32,
// 256 thr, 4 waves (each 64x128), dbuf + counted vmcnt(10). LN computed
// in-block from an LDS h-stage; writes H directly (no h buffer, no ln pass).
// qv/w1: r6 core_db (128x128, dbuf, vmcnt(6)). Swizzle: chunk c^((r>>1)&3)
// applied identically on DMA-source / ds_write and frag_read (involution).
// ws layout (128 MiB, clobber-free):
//   [0,64M)   H (written by intra_ln) ; after qv: zbuf [0,32M), obuf [32,48M)
//   [64M,..)  wb0-3 (stage A only) ; qvout [64M,128M) (stage C+, clobbers wb*)
// ---------------------------------------------------------------------------

typedef __bf16 bf16;
typedef __bf16 bf16x4_t __attribute__((ext_vector_type(4)));
typedef __bf16 bf16x8_t __attribute__((ext_vector_type(8)));
typedef float  f32x4_t  __attribute__((ext_vector_type(4)));

__device__ __forceinline__ bf16x8_t cvt8(f32x4_t a, f32x4_t b) {
  bf16x8_t r;
  r[0] = (bf16)a[0]; r[1] = (bf16)a[1]; r[2] = (bf16)a[2]; r[3] = (bf16)a[3];
  r[4] = (bf16)b[0]; r[5] = (bf16)b[1]; r[6] = (bf16)b[2]; r[7] = (bf16)b[3];
  return r;
}

__device__ __forceinline__ void gl_lds16(const void* g, void* l) {
  __builtin_amdgcn_global_load_lds(
      (const __attribute__((address_space(1))) void*)g,
      (__attribute__((address_space(3))) void*)l, 16, 0, 0);
}

// LDS tiles: rows of 32 bf16 = 4 chunks of 16B; logical chunk c of row r at
// physical chunk c ^ ((r>>1)&3) (involution, <=2-way banks).
__device__ __forceinline__ bf16x8_t frag_read(const bf16* Ts, int row, int c0) {
  const int byte = row * 64 + ((c0 ^ ((row >> 1) & 3)) << 4);
  return *(const bf16x8_t*)((const char*)Ts + byte);
}

// DMA-stage 128x32 bf16 tile (r6): linear LDS dest, source-side swizzle.
__device__ __forceinline__ void stage_b16(const bf16* __restrict__ src, int ld,
                                          int k0, bf16* lds) {
  const int l = threadIdx.x & 63;
  const int w = threadIdx.x >> 6;
#pragma unroll
  for (int j = 0; j < 2; ++j) {
    const int rb = w * 32 + j * 16;
    const int r  = rb + (l >> 2);
    const int sc = (l & 3) ^ ((r >> 1) & 3);
    gl_lds16(src + (size_t)r * ld + k0 + sc * 8, (char*)lds + rb * 64);
  }
}

// DMA-stage 512x32 bf16 tile (8 gl_lds per thread).
__device__ __forceinline__ void stage_b512(const bf16* __restrict__ src, int ld,
                                           int k0, bf16* lds) {
  const int l = threadIdx.x & 63;
  const int w = threadIdx.x >> 6;
#pragma unroll
  for (int j = 0; j < 8; ++j) {
    const int rb = w * 128 + j * 16;
    const int r  = rb + (l >> 2);
    const int sc = (l & 3) ^ ((r >> 1) & 3);
    gl_lds16(src + (size_t)r * ld + k0 + sc * 8, (char*)lds + rb * 64);
  }
}

// commit 16 f32 (4 f32x4) as 2 swizzled chunks (r6, for 128-row reg tiles)
__device__ __forceinline__ void commit2(const f32x4_t v[4], bf16* lds,
                                        int srow, int shalf) {
  const int sw = (srow >> 1) & 3;
  *(bf16x8_t*)((char*)lds + srow * 64 + (((shalf * 2)     ^ sw) << 4)) = cvt8(v[0], v[1]);
  *(bf16x8_t*)((char*)lds + srow * 64 + (((shalf * 2 + 1) ^ sw) << 4)) = cvt8(v[2], v[3]);
}

// MFMA 128x128 step (r6): 4x4 fragments per wave, 2x2 wave grid
__device__ __forceinline__ void mfma_step(const bf16* As, const bf16* Bs,
                                          f32x4_t acc[4][4]) {
  const int lane = threadIdx.x & 63;
  const int wid  = threadIdx.x >> 6;
  const int wm = wid >> 1, wn = wid & 1;
  const int fr = lane & 15, c0 = lane >> 4;
  bf16x8_t ar[4], br[4];
#pragma unroll
  for (int mi = 0; mi < 4; ++mi) ar[mi] = frag_read(As, wm * 64 + mi * 16 + fr, c0);
#pragma unroll
  for (int ni = 0; ni < 4; ++ni) br[ni] = frag_read(Bs, wn * 64 + ni * 16 + fr, c0);
#pragma unroll
  for (int mi = 0; mi < 4; ++mi)
#pragma unroll
    for (int ni = 0; ni < 4; ++ni)
      acc[mi][ni] = __builtin_amdgcn_mfma_f32_16x16x32_bf16(ar[mi], br[ni], acc[mi][ni], 0, 0, 0);
}

// MFMA 64x512 step: 4x8 fragments per wave, 1x4 wave grid (wave = 64x128)
__device__ __forceinline__ void mfma_step8(const bf16* As, const bf16* Bs,
                                           f32x4_t acc[4][8]) {
  const int lane = threadIdx.x & 63;
  const int wn   = threadIdx.x >> 6;
  const int fr = lane & 15, c0 = lane >> 4;
  bf16x8_t ar[4], br[8];
#pragma unroll
  for (int mi = 0; mi < 4; ++mi) ar[mi] = frag_read(As, mi * 16 + fr, c0);
#pragma unroll
  for (int ni = 0; ni < 8; ++ni) br[ni] = frag_read(Bs, wn * 128 + ni * 16 + fr, c0);
#pragma unroll
  for (int mi = 0; mi < 4; ++mi)
#pragma unroll
    for (int ni = 0; ni < 8; ++ni)
      acc[mi][ni] = __builtin_amdgcn_mfma_f32_16x16x32_bf16(ar[mi], br[ni], acc[mi][ni], 0, 0, 0);
}

#define WAIT_VM6()  asm volatile("s_waitcnt vmcnt(6)" ::: "memory")
#define WAIT_VM10() asm volatile("s_waitcnt vmcnt(10)" ::: "memory")
#define WAIT_VM0()  asm volatile("s_waitcnt vmcnt(0)" ::: "memory")
#define WAIT_LGKM() asm volatile("s_waitcnt lgkmcnt(0)" ::: "memory")
#define SBAR()      __builtin_amdgcn_s_barrier()
#define SCHED0()    __builtin_amdgcn_sched_barrier(0)

// r6 double-buffered 128x128 core, counted vmcnt(6).
template<int REG_IS_A>
__device__ __forceinline__ void core_db(
    const float* __restrict__ regsrc, int rld,
    const bf16* __restrict__ dmasrc, int dld, int K,
    bf16* R0, bf16* R1, bf16* D0, bf16* D1, f32x4_t acc[4][4])
{
  const int tid  = threadIdx.x;
  const int srow = tid >> 1, shalf = tid & 1;
  const float* Rf = regsrc + (size_t)srow * rld + shalf * 16;

  f32x4_t ra[4], rb[4];
#pragma unroll
  for (int i = 0; i < 4; ++i) ra[i] = *(const f32x4_t*)(Rf + i * 4);
  stage_b16(dmasrc, dld, 0, D0);

  for (int k0 = 0; k0 < K; k0 += 64) {
    stage_b16(dmasrc, dld, k0 + 32, D1);
#pragma unroll
    for (int i = 0; i < 4; ++i) rb[i] = *(const f32x4_t*)(Rf + k0 + 32 + i * 4);
    WAIT_VM6();
    commit2(ra, R0, srow, shalf);
    WAIT_LGKM();
    SBAR(); SCHED0();
    if (REG_IS_A) mfma_step(R0, D0, acc); else mfma_step(D0, R0, acc);
    SCHED0(); SBAR();
    if (k0 + 64 < K) {
      stage_b16(dmasrc, dld, k0 + 64, D0);
#pragma unroll
      for (int i = 0; i < 4; ++i) ra[i] = *(const f32x4_t*)(Rf + k0 + 64 + i * 4);
      WAIT_VM6();
    } else {
      WAIT_VM0();
    }
    commit2(rb, R1, srow, shalf);
    WAIT_LGKM();
    SBAR(); SCHED0();
    if (REG_IS_A) mfma_step(R1, D1, acc); else mfma_step(D1, R1, acc);
    SCHED0(); SBAR();
  }
}

// epilogue for 128x128 core
template<int RELU>
__device__ __forceinline__ void epi_bf16(f32x4_t acc[4][4], bf16* __restrict__ C, int ldc,
                                         const float* __restrict__ bias) {
  const int lane = threadIdx.x & 63;
  const int wid  = threadIdx.x >> 6;
  const int wm = wid >> 1, wn = wid & 1;
  const int fr = lane & 15;
  const int rb = wm * 64 + 4 * (lane >> 4);
  const int cb = wn * 64 + fr;
  float bv[4];
#pragma unroll
  for (int ni = 0; ni < 4; ++ni) bv[ni] = bias[cb + ni * 16];
#pragma unroll
  for (int mi = 0; mi < 4; ++mi)
#pragma unroll
    for (int j = 0; j < 4; ++j)
#pragma unroll
      for (int ni = 0; ni < 4; ++ni) {
        float val = acc[mi][ni][j] + bv[ni];
        if (RELU) val = fmaxf(val, 0.f);
        C[(size_t)(rb + mi * 16 + j) * ldc + cb + ni * 16] = (bf16)val;
      }
}

// ---- prep: convert intra weights f32 -> bf16 ----
__device__ __forceinline__ void cp8(bf16* d, const float* s) {
  f32x4_t x0 = *(const f32x4_t*)s;
  f32x4_t x1 = *(const f32x4_t*)(s + 4);
  *(bf16x8_t*)d = cvt8(x0, x1);
}

__global__ __launch_bounds__(256) void prep_kernel(
    const float* __restrict__ w0, const float* __restrict__ w1s,
    const float* __restrict__ w2, const float* __restrict__ w3,
    bf16* __restrict__ o0, bf16* __restrict__ o1,
    bf16* __restrict__ o2, bf16* __restrict__ o3) {
  const int t = blockIdx.x * 256 + threadIdx.x;
  if (t < 65536)       { size_t i = (size_t)t * 8;            cp8(o0 + i, w0 + i); }
  else if (t < 114688) { size_t i = (size_t)(t - 65536) * 8;  cp8(o1 + i, w1s + i); }
  else if (t < 147456) { size_t i = (size_t)(t - 114688) * 8; cp8(o2 + i, w2 + i); }
  else                 { size_t i = (size_t)(t - 147456) * 8; cp8(o3 + i, w3 + i); }
}

// ---- stage A (fused): intra GEMM(64x512) + relu + LayerNorm -> H bf16 ----
__global__ __launch_bounds__(256, 2) void intra_ln_kernel(
    const float* __restrict__ f0, const float* __restrict__ f1,
    const float* __restrict__ f2, const float* __restrict__ f3,
    const bf16* __restrict__ wb0, const bf16* __restrict__ wb1,
    const bf16* __restrict__ wb2, const bf16* __restrict__ wb3,
    const float* __restrict__ bb0, const float* __restrict__ bb1,
    const float* __restrict__ bb2, const float* __restrict__ bb3,
    const float* __restrict__ lng, const float* __restrict__ lnb,
    bf16* __restrict__ Hout) {
  __shared__ __align__(16) char smem[73728];     // 72 KiB -> 2 blocks/CU
  bf16* B0 = (bf16*)smem;                        // 32K
  bf16* B1 = (bf16*)(smem + 32768);              // 32K
  bf16* A0 = (bf16*)(smem + 65536);              // 4K
  bf16* A1 = (bf16*)(smem + 69632);              // 4K
  bf16* hl = (bf16*)smem;                        // 64K h-stage (after K-loop)

  const int bid = blockIdx.x;                    // 1024 blocks
  const int lid = (bid & 7) * 128 + (bid >> 3);  // XCD-chunked bijection
  const int z = lid & 3;                         // model
  const int y = lid >> 2;                        // M-block (0..255), 64 rows each
  const float* fp; const bf16* wp; const float* bp; int K;
  switch (z) {
    case 0:  fp = f0; wp = wb0; bp = bb0; K = 1024; break;
    case 1:  fp = f1; wp = wb1; bp = bb1; K = 768;  break;
    case 2:  fp = f2; wp = wb2; bp = bb2; K = 512;  break;
    default: fp = f3; wp = wb3; bp = bb3; K = 640;  break;
  }
  const int tid  = threadIdx.x;
  const int lane = tid & 63;
  const int wn   = tid >> 6;
  const int srow = tid >> 2, sq = tid & 3;       // A staging: 4 thr/row, 8 f32 each
  const float* Af = fp + (size_t)(y * 64 + srow) * K + sq * 8;
  const int abyte = srow * 64 + ((sq ^ ((srow >> 1) & 3)) << 4);

  f32x4_t acc[4][8];
#pragma unroll
  for (int i = 0; i < 4; ++i)
#pragma unroll
    for (int j = 0; j < 8; ++j) acc[i][j] = (f32x4_t){0.f, 0.f, 0.f, 0.f};

  f32x4_t ra0, ra1, rb0, rb1;
  ra0 = *(const f32x4_t*)(Af + 0);  ra1 = *(const f32x4_t*)(Af + 4);
  stage_b512(wp, K, 0, B0);                      // 8 gl_lds (+2 loads above = 10)

  for (int k0 = 0; k0 < K; k0 += 64) {
    // half 1: compute tile k0 (A0,B0); prefetch k0+32 -> (A1,B1)
    stage_b512(wp, K, k0 + 32, B1);
    rb0 = *(const f32x4_t*)(Af + k0 + 32);  rb1 = *(const f32x4_t*)(Af + k0 + 36);
    WAIT_VM10();
    { f32x4_t v[1]; (void)v; }
    *(bf16x8_t*)((char*)A0 + abyte) = cvt8(ra0, ra1);
    WAIT_LGKM();
    SBAR(); SCHED0();
    mfma_step8(A0, B0, acc);
    SCHED0(); SBAR();
    // half 2: compute tile k0+32 (A1,B1); prefetch k0+64 -> (A0,B0)
    if (k0 + 64 < K) {
      stage_b512(wp, K, k0 + 64, B0);
      ra0 = *(const f32x4_t*)(Af + k0 + 64);  ra1 = *(const f32x4_t*)(Af + k0 + 68);
      WAIT_VM10();
    } else {
      WAIT_VM0();
    }
    *(bf16x8_t*)((char*)A1 + abyte) = cvt8(rb0, rb1);
    WAIT_LGKM();
    SBAR(); SCHED0();
    mfma_step8(A1, B1, acc);
    SCHED0(); SBAR();
  }

  // ---- epilogue: bias + relu -> hl[64][512] (bf16) ----
  const int fr = lane & 15;
  const int rbase = 4 * (lane >> 4);
  const int cb = wn * 128 + fr;
  float bv[8];
#pragma unroll
  for (int ni = 0; ni < 8; ++ni) bv[ni] = bp[cb + ni * 16];
#pragma unroll
  for (int mi = 0; mi < 4; ++mi)
#pragma unroll
    for (int j = 0; j < 4; ++j) {
      const int row = mi * 16 + rbase + j;
#pragma unroll
      for (int ni = 0; ni < 8; ++ni) {
        float v = fmaxf(acc[mi][ni][j] + bv[ni], 0.f);
        hl[row * 512 + cb + ni * 16] = (bf16)v;
      }
    }
  __syncthreads();

  // ---- LayerNorm: wave wn handles rows wn*16..+15; lane covers 8 cols ----
  f32x4_t g0 = *(const f32x4_t*)(lng + lane * 8);
  f32x4_t g1 = *(const f32x4_t*)(lng + lane * 8 + 4);
  f32x4_t be0 = *(const f32x4_t*)(lnb + lane * 8);
  f32x4_t be1 = *(const f32x4_t*)(lnb + lane * 8 + 4);
#pragma unroll
  for (int r16 = 0; r16 < 16; ++r16) {
    const int row = wn * 16 + r16;
    const bf16x8_t xv = *(const bf16x8_t*)(hl + row * 512 + lane * 8);
    float xf[8]; float s = 0.f, s2 = 0.f;
#pragma unroll
    for (int j = 0; j < 8; ++j) { xf[j] = (float)xv[j]; s += xf[j]; s2 += xf[j] * xf[j]; }
#pragma unroll
    for (int off = 1; off < 64; off <<= 1) { s += __shfl_xor(s, off); s2 += __shfl_xor(s2, off); }
    const float mu  = s * (1.f / 512.f);
    const float var = s2 * (1.f / 512.f) - mu * mu;
    const float inv = rsqrtf(var + 1e-5f);
    bf16x8_t o;
#pragma unroll
    for (int j = 0; j < 4; ++j) o[j]     = (bf16)((xf[j] - mu) * inv * g0[j] + be0[j]);
#pragma unroll
    for (int j = 0; j < 4; ++j) o[4 + j] = (bf16)((xf[4 + j] - mu) * inv * g1[j] + be1[j]);
    *(bf16x8_t*)(Hout + (size_t)(y * 64 + row) * 2048 + z * 512 + lane * 8) = o;
  }
}

// ---- stage C: fused q||v projection (65536 x 512, K=512) ----
__global__ __launch_bounds__(256) void qv_kernel(
    const bf16* __restrict__ H, const float* __restrict__ Wq,
    const float* __restrict__ Wv, const float* __restrict__ bq,
    const float* __restrict__ bv, bf16* __restrict__ qvout) {
  __shared__ bf16 A0[128 * 32], A1[128 * 32], B0[128 * 32], B1[128 * 32];
  const int bid = blockIdx.x;                     // 2048 blocks
  const int lid = (bid & 7) * 256 + (bid >> 3);
  const int x = lid & 3, y = lid >> 2;            // y: 0..511
  const float* Wsrc = (x < 2) ? Wq : Wv;
  f32x4_t acc[4][4];
#pragma unroll
  for (int i = 0; i < 4; ++i)
#pragma unroll
    for (int j = 0; j < 4; ++j) acc[i][j] = (f32x4_t){0.f, 0.f, 0.f, 0.f};
  core_db<0>(Wsrc + (size_t)((x & 1) * 128) * 512, 512,
             H + (size_t)(y * 128) * 512, 512, 512, B0, B1, A0, A1, acc);
  const float* bias = (x < 2) ? bq + x * 128 : bv + (x - 2) * 128;
  epi_bf16<0>(acc, qvout + (size_t)(y * 128) * 512 + x * 128, 512, bias);
}

// ---- stage E: W1 GEMM (K=1024, ldw=1028) + pred_scores rank-4 fixup ----
__global__ __launch_bounds__(256) void w1_kernel(
    const bf16* __restrict__ zb, const float* __restrict__ W1,
    const float* __restrict__ b1, const float* __restrict__ ps,
    float* __restrict__ obuf) {
  __shared__ bf16 A0[128 * 32], A1[128 * 32], B0[128 * 32], B1[128 * 32];
  const int bid = blockIdx.x;                     // 256 blocks
  const int lid = (bid & 7) * 32 + (bid >> 3);
  const int x = lid & 1, y = lid >> 1;            // y: 0..127
  f32x4_t acc[4][4];
#pragma unroll
  for (int i = 0; i < 4; ++i)
#pragma unroll
    for (int j = 0; j < 4; ++j) acc[i][j] = (f32x4_t){0.f, 0.f, 0.f, 0.f};
  core_db<0>(W1 + (size_t)(x * 128) * 1028, 1028,
             zb + (size_t)(y * 128) * 1024, 1024, 1024, B0, B1, A0, A1, acc);

  const int lane = threadIdx.x & 63;
  const int wid  = threadIdx.x >> 6;
  const int wm = wid >> 1, wn = wid & 1;
  const int fr = lane & 15;
  const int rb = wm * 64 + 4 * (lane >> 4);
  const int cb = x * 128 + wn * 64 + fr;          // global col
  float bv[4], wt[4][4];
#pragma unroll
  for (int ni = 0; ni < 4; ++ni) {
    bv[ni] = b1[cb + ni * 16];
#pragma unroll
    for (int m = 0; m < 4; ++m) wt[ni][m] = W1[(size_t)(cb + ni * 16) * 1028 + 1024 + m];
  }
#pragma unroll
  for (int mi = 0; mi < 4; ++mi)
#pragma unroll
    for (int j = 0; j < 4; ++j) {
      const int r = y * 128 + rb + mi * 16 + j;   // global row
      f32x4_t psv = *(const f32x4_t*)(ps + (size_t)r * 4);
#pragma unroll
      for (int ni = 0; ni < 4; ++ni) {
        float val = acc[mi][ni][j] + bv[ni]
                  + psv[0] * wt[ni][0] + psv[1] * wt[ni][1]
                  + psv[2] * wt[ni][2] + psv[3] * wt[ni][3];
        obuf[(size_t)r * 256 + cb + ni * 16] = val;
      }
    }
}

// ---- attention: 4x4 scores (k=q per source bug), softmax(-UW*(vi+vj)), z=s@v ----
__global__ __launch_bounds__(256)
void attn_kernel(const bf16* __restrict__ qv, const float* __restrict__ pvars,
                 bf16* __restrict__ z) {
  const int b    = blockIdx.x * 4 + (threadIdx.x >> 6);
  const int lane = threadIdx.x & 63;
  float qf[4][4], vf[4][4];
#pragma unroll
  for (int i = 0; i < 4; ++i) {
    const bf16* row = qv + ((size_t)b * 4 + i) * 512;
    bf16x4_t qq = *(const bf16x4_t*)(row + lane * 4);
    bf16x4_t vv = *(const bf16x4_t*)(row + 256 + lane * 4);
#pragma unroll
    for (int c = 0; c < 4; ++c) { qf[i][c] = (float)qq[c]; vf[i][c] = (float)vv[c]; }
  }
  float s[4][4];
#pragma unroll
  for (int i = 0; i < 4; ++i)
#pragma unroll
    for (int j = 0; j < 4; ++j)
      s[i][j] = qf[i][0] * qf[j][0] + qf[i][1] * qf[j][1] + qf[i][2] * qf[j][2] + qf[i][3] * qf[j][3];
#pragma unroll
  for (int off = 1; off < 64; off <<= 1)
#pragma unroll
    for (int i = 0; i < 4; ++i)
#pragma unroll
      for (int j = 0; j < 4; ++j) s[i][j] += __shfl_xor(s[i][j], off);

  float var4[4];
#pragma unroll
  for (int m = 0; m < 4; ++m) var4[m] = pvars[(size_t)b * 4 + m];
  float w[4][4];
#pragma unroll
  for (int i = 0; i < 4; ++i) {
    float t[4]; float mx = -1e30f;
#pragma unroll
    for (int j = 0; j < 4; ++j) { t[j] = s[i][j] - 0.1f * (var4[i] + var4[j]); mx = fmaxf(mx, t[j]); }
    float sum = 0.f;
#pragma unroll
    for (int j = 0; j < 4; ++j) { t[j] = expf(t[j] - mx); sum += t[j]; }
    const float is = 1.f / sum;
#pragma unroll
    for (int j = 0; j < 4; ++j) w[i][j] = t[j] * is;
  }
#pragma unroll
  for (int i = 0; i < 4; ++i) {
    bf16x4_t zo;
#pragma unroll
    for (int c = 0; c < 4; ++c) {
      float zf = w[i][0] * vf[0][c] + w[i][1] * vf[1][c] + w[i][2] * vf[2][c] + w[i][3] * vf[3][c];
      zo[c] = (bf16)zf;
    }
    *(bf16x4_t*)(z + ((size_t)b * 4 + i) * 256 + lane * 4) = zo;
  }
}

// ---- final fc (256 -> 1) + sigmoid ----
__global__ __launch_bounds__(256)
void fc_kernel(const float* __restrict__ o, const float* __restrict__ wfc,
               const float* __restrict__ bfc, float* __restrict__ out) {
  const int b    = blockIdx.x * 4 + (threadIdx.x >> 6);
  const int lane = threadIdx.x & 63;
  f32x4_t ov = *(const f32x4_t*)(o + (size_t)b * 256 + lane * 4);
  f32x4_t wv = *(const f32x4_t*)(wfc + lane * 4);
  float p = ov[0] * wv[0] + ov[1] * wv[1] + ov[2] * wv[2] + ov[3] * wv[3];
#pragma unroll
  for (int off = 1; off < 64; off <<= 1) p += __shfl_xor(p, off);
  if (lane == 0) {
    const float lg = p + bfc[0];
    out[b] = 1.f / (1.f + expf(-lg));
  }
}

extern "C" void kernel_launch(void* const* d_in, const int* in_sizes, int n_in,
                              void* d_out, int out_size, void* d_ws, size_t ws_size,
                              hipStream_t stream) {
  (void)in_sizes; (void)n_in; (void)out_size; (void)ws_size;
  const float* feat[4] = {(const float*)d_in[0], (const float*)d_in[3],
                          (const float*)d_in[6], (const float*)d_in[9]};
  const float* Wi[4]   = {(const float*)d_in[1], (const float*)d_in[4],
                          (const float*)d_in[7], (const float*)d_in[10]};
  const float* bi[4]   = {(const float*)d_in[2], (const float*)d_in[5],
                          (const float*)d_in[8], (const float*)d_in[11]};
  const float* ps  = (const float*)d_in[12];
  const float* pv  = (const float*)d_in[13];
  const float* lng = (const float*)d_in[14];
  const float* lnb = (const float*)d_in[15];
  const float* Wq  = (const float*)d_in[16];
  const float* bq  = (const float*)d_in[17];
  const float* Wv  = (const float*)d_in[20];
  const float* bvp = (const float*)d_in[21];
  const float* W1  = (const float*)d_in[22];
  const float* b1  = (const float*)d_in[23];
  const float* Wfc = (const float*)d_in[24];
  const float* bfc = (const float*)d_in[25];

  char* ws = (char*)d_ws;
  const size_t MB = 1024 * 1024;
  bf16*  Hbuf  = (bf16*)ws;                        // [0,64M): H (intra_ln out)
  bf16*  zbuf  = (bf16*)ws;                        // [0,32M): z (after stage C)
  float* obuf  = (float*)(ws + 32 * MB);           // [32M,48M)
  bf16*  wb0   = (bf16*)(ws + 64 * MB);            // stage A only
  bf16*  wb1   = (bf16*)(ws + 65 * MB);
  bf16*  wb2   = (bf16*)(ws + 65 * MB + 786432);
  bf16*  wb3   = (bf16*)(ws + 66 * MB + 262144);
  bf16*  qvout = (bf16*)(ws + 64 * MB);            // stage C (clobbers wb*)

  hipLaunchKernelGGL(prep_kernel, dim3(736), dim3(256), 0, stream,
                     Wi[0], Wi[1], Wi[2], Wi[3], wb0, wb1, wb2, wb3);
  hipLaunchKernelGGL(intra_ln_kernel, dim3(1024), dim3(256), 0, stream,
                     feat[0], feat[1], feat[2], feat[3],
                     wb0, wb1, wb2, wb3, bi[0], bi[1], bi[2], bi[3],
                     lng, lnb, Hbuf);
  hipLaunchKernelGGL(qv_kernel, dim3(2048), dim3(256), 0, stream,
                     Hbuf, Wq, Wv, bq, bvp, qvout);
  hipLaunchKernelGGL(attn_kernel, dim3(16384 / 4), dim3(256), 0, stream, qvout, pv, zbuf);
  hipLaunchKernelGGL(w1_kernel, dim3(256), dim3(256), 0, stream, zbuf, W1, b1, ps, obuf);
  hipLaunchKernelGGL(fc_kernel, dim3(16384 / 4), dim3(256), 0, stream, obuf, Wfc, bfc, (float*)d_out);
}